// Round 1
// baseline (5109.015 us; speedup 1.0000x reference)
//
#include <hip/hip_runtime.h>
#include <hip/hip_bf16.h>

// Problem constants
#define B_   64
#define T_   512
#define EMB_ 256
#define H_   256          // hidden per direction
#define G4_  1024         // 4*H
#define L_   9
#define NROW (B_*T_)      // 32768
#define NG   2048         // both directions' gates

__device__ __forceinline__ float bf2f(unsigned short u) {
    union { unsigned int i; float f; } c; c.i = ((unsigned int)u) << 16; return c.f;
}
__device__ __forceinline__ unsigned short f2bf(float f) {
    union { unsigned int i; float f; } c; c.f = f;
    unsigned int i = c.i;
    unsigned int r = (i + 0x7FFFu + ((i >> 16) & 1u)) >> 16;
    return (unsigned short)r;
}
__device__ __forceinline__ float sigmf(float x) { return 1.0f / (1.0f + __expf(-x)); }
__device__ __forceinline__ float tanh_fast(float x) {
    // tanh(x) = 2/(1+e^{-2x}) - 1
    return 2.0f / (1.0f + __expf(-2.0f * x)) - 1.0f;
}

// ---------------------------------------------------------------------------
// Prepass: transpose w_hh (both dirs) into wT[dir][k][1024]; combined bias
// ---------------------------------------------------------------------------
__global__ void __launch_bounds__(256) prep_w(
    const float* __restrict__ w_hh_f, const float* __restrict__ w_hh_b,
    const float* __restrict__ b_ih_f, const float* __restrict__ b_hh_f,
    const float* __restrict__ b_ih_b, const float* __restrict__ b_hh_b,
    float* __restrict__ wT, float* __restrict__ bias)
{
    int idx = blockIdx.x * 256 + threadIdx.x;   // 0 .. 524287
    if (idx < 262144) {
        int j = idx >> 8, k = idx & 255;
        wT[(size_t)k * 1024 + j] = w_hh_f[idx];
    } else {
        int i2 = idx - 262144;
        int j = i2 >> 8, k = i2 & 255;
        wT[262144 + (size_t)k * 1024 + j] = w_hh_b[i2];
    }
    if (idx < 1024)      bias[idx] = b_ih_f[idx] + b_hh_f[idx];
    else if (idx < 2048) { int j = idx - 1024; bias[idx] = b_ih_b[j] + b_hh_b[j]; }
}

// ---------------------------------------------------------------------------
// xg GEMM: xg[row][n] = sum_k emb[ids[row]][k] * w(n)[k] + bias[n]  (bf16 out)
// row = b*T + t ; n<1024 -> w_ih_f row n ; n>=1024 -> w_ih_b row n-1024
// fp32 tiled, BM=128 BN=128 BK=16, 256 threads, 8x8 micro-tile
// ---------------------------------------------------------------------------
#define BM 128
#define BN 128
#define BK 16
__global__ void __launch_bounds__(256) xg_gemm(
    const float* __restrict__ emb, const int* __restrict__ ids,
    const float* __restrict__ w_f, const float* __restrict__ w_b,
    const float* __restrict__ bias, unsigned short* __restrict__ xg)
{
    __shared__ float As[BK][BM];
    __shared__ float Bs[BK][BN];
    __shared__ int rowtok[BM];
    int tid = threadIdx.x;
    int row0 = blockIdx.x * BM;
    int col0 = blockIdx.y * BN;
    if (tid < BM) rowtok[tid] = ids[row0 + tid];
    __syncthreads();

    int tx = tid & 15, ty = tid >> 4;
    float acc[8][8];
#pragma unroll
    for (int i = 0; i < 8; ++i)
#pragma unroll
        for (int j = 0; j < 8; ++j) acc[i][j] = 0.0f;

    for (int k0 = 0; k0 < EMB_; k0 += BK) {
        // A tile: 128 rows x 16 k  (gathered rows)
#pragma unroll
        for (int l = 0; l < 2; ++l) {
            int idx = tid + l * 256;          // 0..511
            int r  = idx >> 2;                // 0..127
            int kc = (idx & 3) * 4;           // 0,4,8,12
            const float* src = emb + (size_t)rowtok[r] * EMB_ + k0 + kc;
            float4 v = *(const float4*)src;
            As[kc + 0][r] = v.x; As[kc + 1][r] = v.y;
            As[kc + 2][r] = v.z; As[kc + 3][r] = v.w;
        }
        // B tile: 128 cols x 16 k
#pragma unroll
        for (int l = 0; l < 2; ++l) {
            int idx = tid + l * 256;
            int c  = idx >> 2;
            int kc = (idx & 3) * 4;
            int n  = col0 + c;
            const float* wr = (n < 1024) ? (w_f + (size_t)n * EMB_)
                                         : (w_b + (size_t)(n - 1024) * EMB_);
            float4 v = *(const float4*)(wr + k0 + kc);
            Bs[kc + 0][c] = v.x; Bs[kc + 1][c] = v.y;
            Bs[kc + 2][c] = v.z; Bs[kc + 3][c] = v.w;
        }
        __syncthreads();
#pragma unroll
        for (int k = 0; k < BK; ++k) {
            float a[8], b[8];
            *(float4*)&a[0] = *(float4*)&As[k][ty * 8];
            *(float4*)&a[4] = *(float4*)&As[k][ty * 8 + 4];
            *(float4*)&b[0] = *(float4*)&Bs[k][tx * 8];
            *(float4*)&b[4] = *(float4*)&Bs[k][tx * 8 + 4];
#pragma unroll
            for (int i = 0; i < 8; ++i)
#pragma unroll
                for (int j = 0; j < 8; ++j) acc[i][j] += a[i] * b[j];
        }
        __syncthreads();
    }
    // epilogue: add bias, convert to bf16, store
#pragma unroll
    for (int i = 0; i < 8; ++i) {
        size_t row = (size_t)row0 + ty * 8 + i;
#pragma unroll
        for (int j4 = 0; j4 < 2; ++j4) {
            int nb = col0 + tx * 8 + j4 * 4;
            ushort4 o;
            o.x = f2bf(acc[i][j4 * 4 + 0] + bias[nb + 0]);
            o.y = f2bf(acc[i][j4 * 4 + 1] + bias[nb + 1]);
            o.z = f2bf(acc[i][j4 * 4 + 2] + bias[nb + 2]);
            o.w = f2bf(acc[i][j4 * 4 + 3] + bias[nb + 3]);
            *(ushort4*)(xg + row * NG + nb) = o;
        }
    }
}

// ---------------------------------------------------------------------------
// Sequential LSTM: one block per (dir, batch). 256 threads.
// Weights streamed from L2 (wT layout [dir][k][1024]).
// Thread tid: phase1 computes gates 4tid..4tid+3 (consecutive), phase2 owns
// h-dim tid (reads gate quadruple tid, tid+256, tid+512, tid+768 from LDS).
// ---------------------------------------------------------------------------
__global__ void __launch_bounds__(256) lstm_seq(
    const unsigned short* __restrict__ xg, const float* __restrict__ wT,
    float* __restrict__ h_all)
{
    int bid = blockIdx.x;
    int dir = bid >> 6;
    int b   = bid & 63;
    int tid = threadIdx.x;
    __shared__ float h_lds[256];
    __shared__ float g_lds[1024];
    const float* w = wT + (size_t)dir * 256 * 1024;
    float c = 0.0f;
    h_lds[tid] = 0.0f;
    __syncthreads();

    for (int s = 0; s < T_; ++s) {
        int t = dir ? (T_ - 1 - s) : s;
        size_t row = (size_t)b * T_ + t;
        const unsigned short* xgp = xg + row * NG + dir * 1024 + 4 * tid;
        ushort4 xv = *(const ushort4*)xgp;
        float ax = bf2f(xv.x), ay = bf2f(xv.y), az = bf2f(xv.z), aw = bf2f(xv.w);

        // g = xg + h @ w_hh^T  (this thread: 4 consecutive gate outputs)
        for (int k = 0; k < 256; k += 4) {
            float4 hk = *(const float4*)&h_lds[k];          // LDS broadcast
            const float* wk = w + (size_t)k * 1024 + 4 * tid;
            float4 w0 = *(const float4*)(wk);
            float4 w1 = *(const float4*)(wk + 1024);
            float4 w2 = *(const float4*)(wk + 2048);
            float4 w3 = *(const float4*)(wk + 3072);
            ax += hk.x * w0.x + hk.y * w1.x + hk.z * w2.x + hk.w * w3.x;
            ay += hk.x * w0.y + hk.y * w1.y + hk.z * w2.y + hk.w * w3.y;
            az += hk.x * w0.z + hk.y * w1.z + hk.z * w2.z + hk.w * w3.z;
            aw += hk.x * w0.w + hk.y * w1.w + hk.z * w2.w + hk.w * w3.w;
        }
        *(float4*)&g_lds[4 * tid] = make_float4(ax, ay, az, aw);
        __syncthreads();

        float gi = g_lds[tid];
        float gf = g_lds[tid + 256];
        float gg = g_lds[tid + 512];
        float go = g_lds[tid + 768];
        c = sigmf(gf) * c + sigmf(gi) * tanh_fast(gg);
        float h = sigmf(go) * tanh_fast(c);
        h_all[(((size_t)dir * B_ + b) * T_ + t) * H_ + tid] = h;
        h_lds[tid] = h;   // safe: all k-loop reads of old h finished before SYNC_A
        __syncthreads();
    }
}

// ---------------------------------------------------------------------------
// Emissions: em[row][l] = hf . w_cls[l][0:256] + hb . w_cls[l][256:512] + b_cls
// One wave per row, 4 waves per block.
// ---------------------------------------------------------------------------
__global__ void __launch_bounds__(256) emis_k(
    const float* __restrict__ h_all, const float* __restrict__ w_cls,
    const float* __restrict__ b_cls, float* __restrict__ em)
{
    int wid = threadIdx.x >> 6, lane = threadIdx.x & 63;
    size_t row = (size_t)blockIdx.x * 4 + wid;       // b*T + t
    const float* hf = h_all + row * H_;
    const float* hb = h_all + (size_t)B_ * T_ * H_ + row * H_;
    float4 a0 = *(const float4*)(hf + 4 * lane);
    float4 a1 = *(const float4*)(hb + 4 * lane);
#pragma unroll
    for (int l = 0; l < L_; ++l) {
        const float* wr = w_cls + (size_t)l * 512;
        float4 w0 = *(const float4*)(wr + 4 * lane);
        float4 w1 = *(const float4*)(wr + 256 + 4 * lane);
        float d = a0.x * w0.x + a0.y * w0.y + a0.z * w0.z + a0.w * w0.w
                + a1.x * w1.x + a1.y * w1.y + a1.z * w1.z + a1.w * w1.w;
#pragma unroll
        for (int off = 32; off; off >>= 1) d += __shfl_down(d, off);
        if (lane == 0) em[row * L_ + l] = d + b_cls[l];
    }
}

// ---------------------------------------------------------------------------
// CRF NLL: one block (1 wave) per batch element.
// ---------------------------------------------------------------------------
__global__ void __launch_bounds__(64) crf_k(
    const float* __restrict__ em, const int* __restrict__ labels,
    const int* __restrict__ mask, const float* __restrict__ trans,
    const float* __restrict__ startv, const float* __restrict__ endv,
    float* __restrict__ out)
{
    int b = blockIdx.x, lane = threadIdx.x;
    const float* emb_ = em + (size_t)b * T_ * L_;
    const int* lab = labels + (size_t)b * T_;
    const int* msk = mask + (size_t)b * T_;
    __shared__ float alpha[L_];
    __shared__ float trs[81];
    for (int i = lane; i < 81; i += 64) trs[i] = trans[i];
    __syncthreads();

    // numerator (lane-parallel over t)
    float np = 0.0f;
    for (int t = 1 + lane; t < T_; t += 64)
        if (msk[t]) np += trs[lab[t - 1] * L_ + lab[t]] + emb_[(size_t)t * L_ + lab[t]];
    int mc = 0;
    for (int t = lane; t < T_; t += 64) mc += (msk[t] != 0);
#pragma unroll
    for (int off = 32; off; off >>= 1) {
        np += __shfl_down(np, off);
        mc += __shfl_down(mc, off);
    }
    float num = 0.0f;
    if (lane == 0) {
        int last = mc - 1;
        num = np + startv[lab[0]] + emb_[lab[0]] + endv[lab[last]];
    }

    // forward algorithm
    if (lane < L_) alpha[lane] = startv[lane] + emb_[lane];
    __syncthreads();
    for (int t = 1; t < T_; ++t) {
        float na = 0.0f;
        if (lane < L_) {
            float m = -1e30f;
#pragma unroll
            for (int i = 0; i < L_; ++i) m = fmaxf(m, alpha[i] + trs[i * L_ + lane]);
            float s = 0.0f;
#pragma unroll
            for (int i = 0; i < L_; ++i) s += __expf(alpha[i] + trs[i * L_ + lane] - m);
            na = m + __logf(s) + emb_[(size_t)t * L_ + lane];
            if (!msk[t]) na = alpha[lane];
        }
        __syncthreads();
        if (lane < L_) alpha[lane] = na;
        __syncthreads();
    }
    float v = (lane < L_) ? alpha[lane] + endv[lane] : -1e30f;
    float m = v;
#pragma unroll
    for (int off = 32; off; off >>= 1) m = fmaxf(m, __shfl_xor(m, off));
    float s = (lane < L_) ? __expf(v - m) : 0.0f;
#pragma unroll
    for (int off = 32; off; off >>= 1) s += __shfl_xor(s, off);
    if (lane == 0) {
        float logZ = m + __logf(s);
        atomicAdd(out, (logZ - num) / (float)B_);
    }
}

__global__ void zero_out_k(float* out) { out[0] = 0.0f; }
__global__ void ws_fail_k(float* out, float v) { out[0] = v; }

// ---------------------------------------------------------------------------
extern "C" void kernel_launch(void* const* d_in, const int* in_sizes, int n_in,
                              void* d_out, int out_size, void* d_ws, size_t ws_size,
                              hipStream_t stream)
{
    const int*   ids    = (const int*)  d_in[0];
    const int*   amask  = (const int*)  d_in[1];
    const int*   labels = (const int*)  d_in[2];
    const float* emb    = (const float*)d_in[3];
    const float* w_ih_f = (const float*)d_in[4];
    const float* w_hh_f = (const float*)d_in[5];
    const float* b_ih_f = (const float*)d_in[6];
    const float* b_hh_f = (const float*)d_in[7];
    const float* w_ih_b = (const float*)d_in[8];
    const float* w_hh_b = (const float*)d_in[9];
    const float* b_ih_b = (const float*)d_in[10];
    const float* b_hh_b = (const float*)d_in[11];
    const float* w_cls  = (const float*)d_in[12];
    const float* b_cls  = (const float*)d_in[13];
    const float* trans  = (const float*)d_in[14];
    const float* startv = (const float*)d_in[15];
    const float* endv   = (const float*)d_in[16];
    float* out = (float*)d_out;

    // workspace layout
    size_t o_xg   = 0;                                   // bf16 xg: 32768*2048*2
    size_t o_wT   = o_xg + (size_t)NROW * NG * 2;        // 134,217,728
    size_t o_bias = o_wT + (size_t)2 * 256 * 1024 * 4;   // +2,097,152
    size_t o_h    = o_bias + 2048 * 4;                   // +8,192
    size_t o_em   = o_h + (size_t)2 * B_ * T_ * H_ * 4;  // +67,108,864
    size_t total  = o_em + (size_t)NROW * L_ * 4;        // +1,179,648 = 204,611,584

    if (ws_size < total) {
        ws_fail_k<<<1, 1, 0, stream>>>(out, -1.0e8f - (float)(ws_size >> 20));
        return;
    }

    unsigned short* xg = (unsigned short*)((char*)d_ws + o_xg);
    float* wT    = (float*)((char*)d_ws + o_wT);
    float* bias  = (float*)((char*)d_ws + o_bias);
    float* h_all = (float*)((char*)d_ws + o_h);
    float* em    = (float*)((char*)d_ws + o_em);

    prep_w<<<2048, 256, 0, stream>>>(w_hh_f, w_hh_b, b_ih_f, b_hh_f, b_ih_b, b_hh_b, wT, bias);
    xg_gemm<<<dim3(NROW / BM, NG / BN), 256, 0, stream>>>(emb, ids, w_ih_f, w_ih_b, bias, xg);
    lstm_seq<<<128, 256, 0, stream>>>(xg, wT, h_all);
    emis_k<<<NROW / 4, 256, 0, stream>>>(h_all, w_cls, b_cls, em);
    zero_out_k<<<1, 1, 0, stream>>>(out);
    crf_k<<<B_, 64, 0, stream>>>(em, labels, amask, trans, startv, endv, out);
}

// Round 2
// 4799.183 us; speedup vs baseline: 1.0646x; 1.0646x over previous
//
#include <hip/hip_runtime.h>
#include <hip/hip_bf16.h>

// Problem constants
#define B_   64
#define T_   512
#define EMB_ 256
#define H_   256          // hidden per direction
#define G4_  1024         // 4*H
#define L_   9
#define NROW (B_*T_)      // 32768
#define NG   2048         // both directions' gates

__device__ __forceinline__ float bf2f(unsigned short u) {
    union { unsigned int i; float f; } c; c.i = ((unsigned int)u) << 16; return c.f;
}
__device__ __forceinline__ unsigned short f2bf(float f) {
    union { unsigned int i; float f; } c; c.f = f;
    unsigned int i = c.i;
    unsigned int r = (i + 0x7FFFu + ((i >> 16) & 1u)) >> 16;
    return (unsigned short)r;
}
__device__ __forceinline__ float sigmf(float x) { return 1.0f / (1.0f + __expf(-x)); }
__device__ __forceinline__ float tanh_fast(float x) {
    return 2.0f / (1.0f + __expf(-2.0f * x)) - 1.0f;
}

// ---------------------------------------------------------------------------
// Prepass: transpose w_hh (both dirs) to bf16 wTb[dir][k][1024]; combined bias
// ---------------------------------------------------------------------------
__global__ void __launch_bounds__(256) prep_w(
    const float* __restrict__ w_hh_f, const float* __restrict__ w_hh_b,
    const float* __restrict__ b_ih_f, const float* __restrict__ b_hh_f,
    const float* __restrict__ b_ih_b, const float* __restrict__ b_hh_b,
    unsigned short* __restrict__ wTb, float* __restrict__ bias)
{
    int idx = blockIdx.x * 256 + threadIdx.x;   // 0 .. 524287
    if (idx < 262144) {
        int g = idx >> 8, k = idx & 255;
        wTb[(size_t)k * 1024 + g] = f2bf(w_hh_f[idx]);
    } else {
        int i2 = idx - 262144;
        int g = i2 >> 8, k = i2 & 255;
        wTb[262144 + (size_t)k * 1024 + g] = f2bf(w_hh_b[i2]);
    }
    if (idx < 1024)      bias[idx] = b_ih_f[idx] + b_hh_f[idx];
    else if (idx < 2048) { int j = idx - 1024; bias[idx] = b_ih_b[j] + b_hh_b[j]; }
}

// ---------------------------------------------------------------------------
// xg GEMM: xg[row][n] = sum_k emb[ids[row]][k] * w(n)[k] + bias[n]  (bf16 out)
// ---------------------------------------------------------------------------
#define BM 128
#define BN 128
#define BK 16
__global__ void __launch_bounds__(256) xg_gemm(
    const float* __restrict__ emb, const int* __restrict__ ids,
    const float* __restrict__ w_f, const float* __restrict__ w_b,
    const float* __restrict__ bias, unsigned short* __restrict__ xg)
{
    __shared__ float As[BK][BM];
    __shared__ float Bs[BK][BN];
    __shared__ int rowtok[BM];
    int tid = threadIdx.x;
    int row0 = blockIdx.x * BM;
    int col0 = blockIdx.y * BN;
    if (tid < BM) rowtok[tid] = ids[row0 + tid];
    __syncthreads();

    int tx = tid & 15, ty = tid >> 4;
    float acc[8][8];
#pragma unroll
    for (int i = 0; i < 8; ++i)
#pragma unroll
        for (int j = 0; j < 8; ++j) acc[i][j] = 0.0f;

    for (int k0 = 0; k0 < EMB_; k0 += BK) {
#pragma unroll
        for (int l = 0; l < 2; ++l) {
            int idx = tid + l * 256;
            int r  = idx >> 2;
            int kc = (idx & 3) * 4;
            const float* src = emb + (size_t)rowtok[r] * EMB_ + k0 + kc;
            float4 v = *(const float4*)src;
            As[kc + 0][r] = v.x; As[kc + 1][r] = v.y;
            As[kc + 2][r] = v.z; As[kc + 3][r] = v.w;
        }
#pragma unroll
        for (int l = 0; l < 2; ++l) {
            int idx = tid + l * 256;
            int c  = idx >> 2;
            int kc = (idx & 3) * 4;
            int n  = col0 + c;
            const float* wr = (n < 1024) ? (w_f + (size_t)n * EMB_)
                                         : (w_b + (size_t)(n - 1024) * EMB_);
            float4 v = *(const float4*)(wr + k0 + kc);
            Bs[kc + 0][c] = v.x; Bs[kc + 1][c] = v.y;
            Bs[kc + 2][c] = v.z; Bs[kc + 3][c] = v.w;
        }
        __syncthreads();
#pragma unroll
        for (int k = 0; k < BK; ++k) {
            float a[8], b[8];
            *(float4*)&a[0] = *(float4*)&As[k][ty * 8];
            *(float4*)&a[4] = *(float4*)&As[k][ty * 8 + 4];
            *(float4*)&b[0] = *(float4*)&Bs[k][tx * 8];
            *(float4*)&b[4] = *(float4*)&Bs[k][tx * 8 + 4];
#pragma unroll
            for (int i = 0; i < 8; ++i)
#pragma unroll
                for (int j = 0; j < 8; ++j) acc[i][j] += a[i] * b[j];
        }
        __syncthreads();
    }
#pragma unroll
    for (int i = 0; i < 8; ++i) {
        size_t row = (size_t)row0 + ty * 8 + i;
#pragma unroll
        for (int j4 = 0; j4 < 2; ++j4) {
            int nb = col0 + tx * 8 + j4 * 4;
            ushort4 o;
            o.x = f2bf(acc[i][j4 * 4 + 0] + bias[nb + 0]);
            o.y = f2bf(acc[i][j4 * 4 + 1] + bias[nb + 1]);
            o.z = f2bf(acc[i][j4 * 4 + 2] + bias[nb + 2]);
            o.w = f2bf(acc[i][j4 * 4 + 3] + bias[nb + 3]);
            *(ushort4*)(xg + row * NG + nb) = o;
        }
    }
}

// ---------------------------------------------------------------------------
// Sequential LSTM: one block per (dir, batch), 512 threads (8 waves).
// Thread (g = tid&255, kh = tid>>8): partial gates 4g..4g+3 over k-half kh.
// bf16 weights streamed from L2, layout wTb[dir][k][1024].
// ---------------------------------------------------------------------------
__global__ void __launch_bounds__(512) lstm_seq(
    const unsigned short* __restrict__ xg, const unsigned short* __restrict__ wTb,
    float* __restrict__ h_all)
{
    int bid = blockIdx.x;
    int dir = bid >> 6;
    int b   = bid & 63;
    int tid = threadIdx.x;
    int g   = tid & 255;
    int kh  = tid >> 8;
    __shared__ float h_lds[256];
    __shared__ float pg[2][1024];
    const unsigned short* wb = wTb + (size_t)dir * 256 * 1024
                                   + (size_t)(kh * 128) * 1024 + 4 * g;
    float c = 0.0f;
    if (tid < 256) h_lds[tid] = 0.0f;
    __syncthreads();

    for (int s = 0; s < T_; ++s) {
        int t = dir ? (T_ - 1 - s) : s;
        size_t row = (size_t)b * T_ + t;
        float ax = 0.f, ay = 0.f, az = 0.f, aw = 0.f;
        if (kh == 0) {
            ushort4 xv = *(const ushort4*)(xg + row * NG + dir * 1024 + 4 * g);
            ax = bf2f(xv.x); ay = bf2f(xv.y); az = bf2f(xv.z); aw = bf2f(xv.w);
        }
        const unsigned short* wp = wb;
#pragma unroll 8
        for (int kk = 0; kk < 128; kk += 4) {
            float4 hk = *(const float4*)&h_lds[kh * 128 + kk];
            ushort4 u0 = *(const ushort4*)(wp);
            ushort4 u1 = *(const ushort4*)(wp + 1024);
            ushort4 u2 = *(const ushort4*)(wp + 2048);
            ushort4 u3 = *(const ushort4*)(wp + 3072);
            ax += hk.x * bf2f(u0.x) + hk.y * bf2f(u1.x) + hk.z * bf2f(u2.x) + hk.w * bf2f(u3.x);
            ay += hk.x * bf2f(u0.y) + hk.y * bf2f(u1.y) + hk.z * bf2f(u2.y) + hk.w * bf2f(u3.y);
            az += hk.x * bf2f(u0.z) + hk.y * bf2f(u1.z) + hk.z * bf2f(u2.z) + hk.w * bf2f(u3.z);
            aw += hk.x * bf2f(u0.w) + hk.y * bf2f(u1.w) + hk.z * bf2f(u2.w) + hk.w * bf2f(u3.w);
            wp += 4096;
        }
        *(float4*)&pg[kh][4 * g] = make_float4(ax, ay, az, aw);
        __syncthreads();
        if (tid < 256) {
            float gi = pg[0][tid]       + pg[1][tid];
            float gf = pg[0][tid + 256] + pg[1][tid + 256];
            float gg = pg[0][tid + 512] + pg[1][tid + 512];
            float go = pg[0][tid + 768] + pg[1][tid + 768];
            c = sigmf(gf) * c + sigmf(gi) * tanh_fast(gg);
            float h = sigmf(go) * tanh_fast(c);
            h_all[(((size_t)dir * B_ + b) * T_ + t) * H_ + tid] = h;
            h_lds[tid] = h;
        }
        __syncthreads();
    }
}

// ---------------------------------------------------------------------------
// Emissions
// ---------------------------------------------------------------------------
__global__ void __launch_bounds__(256) emis_k(
    const float* __restrict__ h_all, const float* __restrict__ w_cls,
    const float* __restrict__ b_cls, float* __restrict__ em)
{
    int wid = threadIdx.x >> 6, lane = threadIdx.x & 63;
    size_t row = (size_t)blockIdx.x * 4 + wid;
    const float* hf = h_all + row * H_;
    const float* hb = h_all + (size_t)B_ * T_ * H_ + row * H_;
    float4 a0 = *(const float4*)(hf + 4 * lane);
    float4 a1 = *(const float4*)(hb + 4 * lane);
#pragma unroll
    for (int l = 0; l < L_; ++l) {
        const float* wr = w_cls + (size_t)l * 512;
        float4 w0 = *(const float4*)(wr + 4 * lane);
        float4 w1 = *(const float4*)(wr + 256 + 4 * lane);
        float d = a0.x * w0.x + a0.y * w0.y + a0.z * w0.z + a0.w * w0.w
                + a1.x * w1.x + a1.y * w1.y + a1.z * w1.z + a1.w * w1.w;
#pragma unroll
        for (int off = 32; off; off >>= 1) d += __shfl_down(d, off);
        if (lane == 0) em[row * L_ + l] = d + b_cls[l];
    }
}

// ---------------------------------------------------------------------------
// CRF NLL
// ---------------------------------------------------------------------------
__global__ void __launch_bounds__(64) crf_k(
    const float* __restrict__ em, const int* __restrict__ labels,
    const int* __restrict__ mask, const float* __restrict__ trans,
    const float* __restrict__ startv, const float* __restrict__ endv,
    float* __restrict__ out)
{
    int b = blockIdx.x, lane = threadIdx.x;
    const float* emb_ = em + (size_t)b * T_ * L_;
    const int* lab = labels + (size_t)b * T_;
    const int* msk = mask + (size_t)b * T_;
    __shared__ float alpha[L_];
    __shared__ float trs[81];
    for (int i = lane; i < 81; i += 64) trs[i] = trans[i];
    __syncthreads();

    float np = 0.0f;
    for (int t = 1 + lane; t < T_; t += 64)
        if (msk[t]) np += trs[lab[t - 1] * L_ + lab[t]] + emb_[(size_t)t * L_ + lab[t]];
    int mc = 0;
    for (int t = lane; t < T_; t += 64) mc += (msk[t] != 0);
#pragma unroll
    for (int off = 32; off; off >>= 1) {
        np += __shfl_down(np, off);
        mc += __shfl_down(mc, off);
    }
    float num = 0.0f;
    if (lane == 0) {
        int last = mc - 1;
        num = np + startv[lab[0]] + emb_[lab[0]] + endv[lab[last]];
    }

    if (lane < L_) alpha[lane] = startv[lane] + emb_[lane];
    __syncthreads();
    for (int t = 1; t < T_; ++t) {
        float na = 0.0f;
        if (lane < L_) {
            float m = -1e30f;
#pragma unroll
            for (int i = 0; i < L_; ++i) m = fmaxf(m, alpha[i] + trs[i * L_ + lane]);
            float s = 0.0f;
#pragma unroll
            for (int i = 0; i < L_; ++i) s += __expf(alpha[i] + trs[i * L_ + lane] - m);
            na = m + __logf(s) + emb_[(size_t)t * L_ + lane];
            if (!msk[t]) na = alpha[lane];
        }
        __syncthreads();
        if (lane < L_) alpha[lane] = na;
        __syncthreads();
    }
    float v = (lane < L_) ? alpha[lane] + endv[lane] : -1e30f;
    float m = v;
#pragma unroll
    for (int off = 32; off; off >>= 1) m = fmaxf(m, __shfl_xor(m, off));
    float s = (lane < L_) ? __expf(v - m) : 0.0f;
#pragma unroll
    for (int off = 32; off; off >>= 1) s += __shfl_xor(s, off);
    if (lane == 0) {
        float logZ = m + __logf(s);
        atomicAdd(out, (logZ - num) / (float)B_);
    }
}

__global__ void zero_out_k(float* out) { out[0] = 0.0f; }
__global__ void ws_fail_k(float* out, float v) { out[0] = v; }

// ---------------------------------------------------------------------------
extern "C" void kernel_launch(void* const* d_in, const int* in_sizes, int n_in,
                              void* d_out, int out_size, void* d_ws, size_t ws_size,
                              hipStream_t stream)
{
    const int*   ids    = (const int*)  d_in[0];
    const int*   amask  = (const int*)  d_in[1];
    const int*   labels = (const int*)  d_in[2];
    const float* emb    = (const float*)d_in[3];
    const float* w_ih_f = (const float*)d_in[4];
    const float* w_hh_f = (const float*)d_in[5];
    const float* b_ih_f = (const float*)d_in[6];
    const float* b_hh_f = (const float*)d_in[7];
    const float* w_ih_b = (const float*)d_in[8];
    const float* w_hh_b = (const float*)d_in[9];
    const float* b_ih_b = (const float*)d_in[10];
    const float* b_hh_b = (const float*)d_in[11];
    const float* w_cls  = (const float*)d_in[12];
    const float* b_cls  = (const float*)d_in[13];
    const float* trans  = (const float*)d_in[14];
    const float* startv = (const float*)d_in[15];
    const float* endv   = (const float*)d_in[16];
    float* out = (float*)d_out;

    // workspace layout
    size_t o_xg   = 0;                                   // bf16 xg: 128 MB
    size_t o_wTb  = o_xg + (size_t)NROW * NG * 2;        // bf16 weights: 1 MB
    size_t o_bias = o_wTb + (size_t)2 * 256 * 1024 * 2;
    size_t o_h    = o_bias + 2048 * 4;
    size_t o_em   = o_h + (size_t)2 * B_ * T_ * H_ * 4;  // 64 MB
    size_t total  = o_em + (size_t)NROW * L_ * 4;

    if (ws_size < total) {
        ws_fail_k<<<1, 1, 0, stream>>>(out, -1.0e8f - (float)(ws_size >> 20));
        return;
    }

    unsigned short* xg  = (unsigned short*)((char*)d_ws + o_xg);
    unsigned short* wTb = (unsigned short*)((char*)d_ws + o_wTb);
    float* bias  = (float*)((char*)d_ws + o_bias);
    float* h_all = (float*)((char*)d_ws + o_h);
    float* em    = (float*)((char*)d_ws + o_em);

    prep_w<<<2048, 256, 0, stream>>>(w_hh_f, w_hh_b, b_ih_f, b_hh_f, b_ih_b, b_hh_b, wTb, bias);
    xg_gemm<<<dim3(NROW / BM, NG / BN), 256, 0, stream>>>(emb, ids, w_ih_f, w_ih_b, bias, xg);
    lstm_seq<<<128, 512, 0, stream>>>(xg, wTb, h_all);
    emis_k<<<NROW / 4, 256, 0, stream>>>(h_all, w_cls, b_cls, em);
    zero_out_k<<<1, 1, 0, stream>>>(out);
    crf_k<<<B_, 64, 0, stream>>>(em, labels, amask, trans, startv, endv, out);
}